// Round 8
// baseline (145.968 us; speedup 1.0000x reference)
//
#include <hip/hip_runtime.h>
#include <hip/hip_cooperative_groups.h>
#include <math.h>

namespace cg = cooperative_groups;

#define BB 32
#define LL 2048
#define DD 256
#define NC 16
#define TPB 256   // 4 waves

// ---------------- cooperative fused config ----------------
#define CS 16                    // chunks per batch row
#define CNBLK (BB * CS)          // 512 blocks = 2 blocks/CU co-resident
#define TOKW 32                  // tokens per wave (128 per block)
#define TREG 16                  // tokens kept in registers per wave
#define TLDS 16                  // tokens kept in LDS per wave
#define NROWS 64                 // TLDS * 4 waves rows in LDS per block

// dynamic smem layout (floats): rows[NROWS*DD] | ml[NROWS] | red[4*DD]
#define SM_ML    (NROWS * DD)
#define SM_RED   (SM_ML + NROWS)
#define SM_FLOATS (SM_RED + 4 * DD)
#define SM_BYTES (SM_FLOATS * sizeof(float))   // ~69.9 KB

// ---------------- fallback config (R4 proven, 33 us) ----------------
#define FSPLIT 32
#define FTOK_CHUNK (LL / FSPLIT)        // 64
#define FTOK_WAVE  (FTOK_CHUNK / 4)     // 16
#define FPF 8

// ws layout (floats), shared by both paths:
//  pes  [32][BB][DD] | plen [32][BB] | pout [32][BB][DD] | pys [32][BB]
//  emb_sum [BB][DD] | lens [BB]     (fallback only)

// ============================ cooperative fused ============================
__global__ __launch_bounds__(TPB, 2) void kFused(
    const int* __restrict__ idx, const float* __restrict__ mask,
    const float4* __restrict__ enc4, const float* __restrict__ dec_w,
    float* __restrict__ pes, float* __restrict__ plen,
    float* __restrict__ pout, float* __restrict__ pys,
    float* __restrict__ out) {
  cg::grid_group grid = cg::this_grid();
  const int b     = blockIdx.x / CS;
  const int chunk = blockIdx.x % CS;
  const int wave  = threadIdx.x >> 6;
  const int lane  = threadIdx.x & 63;
  const int tid   = threadIdx.x;
  const int l0 = chunk * (TOKW * 4) + wave * TOKW;   // this wave's first token

  extern __shared__ float smem[];
  float* rows = smem;             // [NROWS][DD] masked rows
  float* ml   = smem + SM_ML;     // [NROWS] per-row mask
  float* red  = smem + SM_RED;    // [4][DD] block reduction buffer
  __shared__ float small4[4];
  __shared__ float ysum_s, len_s;

  // ---- single gather pass ----
  // register half: tokens l0 .. l0+15
  float mr[TREG];
  float4 wr[TREG];
  {
    int ids[TREG];
    #pragma unroll
    for (int t = 0; t < TREG; ++t) {
      ids[t] = idx[b * LL + l0 + t];
      mr[t]  = mask[b * LL + l0 + t];
    }
    #pragma unroll
    for (int t = 0; t < TREG; ++t) {
      const float4 v = enc4[(size_t)ids[t] * (DD / 4) + lane];
      wr[t].x = v.x * mr[t]; wr[t].y = v.y * mr[t];
      wr[t].z = v.z * mr[t]; wr[t].w = v.w * mr[t];
    }
  }

  float4 acc = {0.f, 0.f, 0.f, 0.f};
  float lenacc = 0.f;
  #pragma unroll
  for (int t = 0; t < TREG; ++t) {
    acc.x += wr[t].x; acc.y += wr[t].y;
    acc.z += wr[t].z; acc.w += wr[t].w;
    lenacc += mr[t];
  }

  // LDS half: tokens l0+16 .. l0+31, in two batches of 8
  #pragma unroll
  for (int g = 0; g < TLDS; g += 8) {
    int id2[8]; float m2[8];
    #pragma unroll
    for (int t = 0; t < 8; ++t) {
      id2[t] = idx[b * LL + l0 + TREG + g + t];
      m2[t]  = mask[b * LL + l0 + TREG + g + t];
    }
    float4 v[8];
    #pragma unroll
    for (int t = 0; t < 8; ++t)
      v[t] = enc4[(size_t)id2[t] * (DD / 4) + lane];
    #pragma unroll
    for (int t = 0; t < 8; ++t) {
      const float m = m2[t];
      v[t].x *= m; v[t].y *= m; v[t].z *= m; v[t].w *= m;
      const int r = wave * TLDS + g + t;
      *reinterpret_cast<float4*>(&rows[r * DD + lane * 4]) = v[t];
      if (lane == 0) ml[r] = m;
      acc.x += v[t].x; acc.y += v[t].y; acc.z += v[t].z; acc.w += v[t].w;
      lenacc += m;
    }
  }

  // ---- phase A: block-partial emb_sum and lens
  red[wave * DD + lane * 4 + 0] = acc.x;
  red[wave * DD + lane * 4 + 1] = acc.y;
  red[wave * DD + lane * 4 + 2] = acc.z;
  red[wave * DD + lane * 4 + 3] = acc.w;
  if (lane == 0) small4[wave] = lenacc;
  __syncthreads();
  {
    const float s = red[0 * DD + tid] + red[1 * DD + tid] +
                    red[2 * DD + tid] + red[3 * DD + tid];
    pes[(chunk * BB + b) * DD + tid] = s;
    if (tid == 0) plen[chunk * BB + b] = small4[0] + small4[1] + small4[2] + small4[3];
  }

  grid.sync();

  // ---- every block reduces emb_sum[b] from the 16 partials
  {
    float es_col = 0.f;
    #pragma unroll
    for (int c = 0; c < CS; ++c) es_col += pes[(c * BB + b) * DD + tid];
    red[tid] = es_col;
  }
  __syncthreads();
  const float4 es = *reinterpret_cast<const float4*>(&red[lane * 4]);
  __syncthreads();

  // ---- phase B: scores + weighted sum from registers/LDS (no re-gather)
  {
    float4 bcc = {0.f, 0.f, 0.f, 0.f};
    float ys = 0.f;
    #pragma unroll
    for (int t = 0; t < TREG; ++t) {
      float d = wr[t].x * es.x + wr[t].y * es.y + wr[t].z * es.z + wr[t].w * es.w;
      #pragma unroll
      for (int off = 32; off > 0; off >>= 1) d += __shfl_xor(d, off);
      const float y = expf(d) * mr[t];     // score = emb_l . emb_sum ; y = exp*mask
      bcc.x += y * wr[t].x; bcc.y += y * wr[t].y;
      bcc.z += y * wr[t].z; bcc.w += y * wr[t].w;
      ys += y;
    }
    #pragma unroll
    for (int t = 0; t < TLDS; ++t) {
      const int r = wave * TLDS + t;
      const float4 w = *reinterpret_cast<const float4*>(&rows[r * DD + lane * 4]);
      const float m = ml[r];
      float d = w.x * es.x + w.y * es.y + w.z * es.z + w.w * es.w;
      #pragma unroll
      for (int off = 32; off > 0; off >>= 1) d += __shfl_xor(d, off);
      const float y = expf(d) * m;
      bcc.x += y * w.x; bcc.y += y * w.y; bcc.z += y * w.z; bcc.w += y * w.w;
      ys += y;
    }
    red[wave * DD + lane * 4 + 0] = bcc.x;
    red[wave * DD + lane * 4 + 1] = bcc.y;
    red[wave * DD + lane * 4 + 2] = bcc.z;
    red[wave * DD + lane * 4 + 3] = bcc.w;
    if (lane == 0) small4[wave] = ys;
    __syncthreads();
    const float s = red[0 * DD + tid] + red[1 * DD + tid] +
                    red[2 * DD + tid] + red[3 * DD + tid];
    pout[(chunk * BB + b) * DD + tid] = s;
    if (tid == 0) pys[chunk * BB + b] = small4[0] + small4[1] + small4[2] + small4[3];
  }

  grid.sync();

  // ---- final: blocks 0..31 reduce partials, normalize, run the head
  if (blockIdx.x < BB) {
    const int b2 = blockIdx.x;
    float os = 0.f, s2 = 0.f;
    #pragma unroll
    for (int c = 0; c < CS; ++c) {
      os += pout[(c * BB + b2) * DD + tid];
      s2 += pes [(c * BB + b2) * DD + tid];
    }
    if (tid < 64) {
      float v = (tid < CS) ? pys[tid * BB + b2] : 0.f;
      #pragma unroll
      for (int off = 16; off > 0; off >>= 1) v += __shfl_xor(v, off);
      if (tid == 0) ysum_s = v;
    } else if (tid < 128) {
      const int t2 = tid - 64;
      float v = (t2 < CS) ? plen[t2 * BB + b2] : 0.f;
      #pragma unroll
      for (int off = 16; off > 0; off >>= 1) v += __shfl_xor(v, off);
      if (t2 == 0) len_s = v;
    }
    __syncthreads();
    red[DD + tid] = os / ysum_s + s2 / len_s;     // vec in red[256..511]
    __syncthreads();
    const float4 vv = *reinterpret_cast<const float4*>(&red[DD + lane * 4]);
    #pragma unroll
    for (int cc = 0; cc < 4; ++cc) {
      const int c = wave * 4 + cc;
      const float4 dw = reinterpret_cast<const float4*>(dec_w)[c * (DD / 4) + lane];
      float d = vv.x * dw.x + vv.y * dw.y + vv.z * dw.z + vv.w * dw.w;
      #pragma unroll
      for (int off = 32; off > 0; off >>= 1) d += __shfl_xor(d, off);
      if (lane == 0) out[b2 * NC + c] = d;
    }
  }
}

// ============================ fallback (R4, proven) ============================
__global__ __launch_bounds__(TPB) void kA_partial(
    const int* __restrict__ idx, const float* __restrict__ mask,
    const float4* __restrict__ enc4,
    float* __restrict__ pes, float* __restrict__ plen) {
  const int b     = blockIdx.x / FSPLIT;
  const int chunk = blockIdx.x % FSPLIT;
  const int wave  = threadIdx.x >> 6;
  const int lane  = threadIdx.x & 63;
  const int tid   = threadIdx.x;
  const int l0 = chunk * FTOK_CHUNK + wave * FTOK_WAVE;

  int   id_r[FTOK_WAVE];
  float m_r[FTOK_WAVE];
  #pragma unroll
  for (int t = 0; t < FTOK_WAVE; ++t) {
    id_r[t] = idx[b * LL + l0 + t];
    m_r[t]  = mask[b * LL + l0 + t];
  }

  float4 acc = {0.f, 0.f, 0.f, 0.f};
  float lenacc = 0.f;
  #pragma unroll
  for (int g = 0; g < FTOK_WAVE; g += FPF) {
    float4 v[FPF];
    #pragma unroll
    for (int t = 0; t < FPF; ++t)
      v[t] = enc4[(size_t)id_r[g + t] * (DD / 4) + lane];
    #pragma unroll
    for (int t = 0; t < FPF; ++t) {
      const float m = m_r[g + t];
      acc.x += v[t].x * m; acc.y += v[t].y * m;
      acc.z += v[t].z * m; acc.w += v[t].w * m;
      lenacc += m;
    }
  }

  __shared__ float lds[4][DD];
  __shared__ float llds[4];
  lds[wave][lane * 4 + 0] = acc.x;
  lds[wave][lane * 4 + 1] = acc.y;
  lds[wave][lane * 4 + 2] = acc.z;
  lds[wave][lane * 4 + 3] = acc.w;
  if (lane == 0) llds[wave] = lenacc;
  __syncthreads();

  const float s = lds[0][tid] + lds[1][tid] + lds[2][tid] + lds[3][tid];
  pes[(chunk * BB + b) * DD + tid] = s;
  if (tid == 0) plen[chunk * BB + b] = llds[0] + llds[1] + llds[2] + llds[3];
}

__global__ __launch_bounds__(TPB) void kR1(
    const float* __restrict__ pes, const float* __restrict__ plen,
    float* __restrict__ emb_sum, float* __restrict__ lens) {
  const int b = blockIdx.x;
  const int tid = threadIdx.x;
  float s = 0.f;
  #pragma unroll
  for (int c = 0; c < FSPLIT; ++c) s += pes[(c * BB + b) * DD + tid];
  emb_sum[b * DD + tid] = s;
  if (tid < 64) {
    float v = (tid < FSPLIT) ? plen[tid * BB + b] : 0.f;
    #pragma unroll
    for (int off = 16; off > 0; off >>= 1) v += __shfl_xor(v, off);
    if (tid == 0) lens[b] = v;
  }
}

__global__ __launch_bounds__(TPB) void kB_partial(
    const int* __restrict__ idx, const float* __restrict__ mask,
    const float4* __restrict__ enc4, const float* __restrict__ emb_sum,
    float* __restrict__ pout, float* __restrict__ pys) {
  const int b     = blockIdx.x / FSPLIT;
  const int chunk = blockIdx.x % FSPLIT;
  const int wave  = threadIdx.x >> 6;
  const int lane  = threadIdx.x & 63;
  const int tid   = threadIdx.x;
  const int l0 = chunk * FTOK_CHUNK + wave * FTOK_WAVE;

  const float4 es = reinterpret_cast<const float4*>(emb_sum)[b * (DD / 4) + lane];

  int   id_r[FTOK_WAVE];
  float m_r[FTOK_WAVE];
  #pragma unroll
  for (int t = 0; t < FTOK_WAVE; ++t) {
    id_r[t] = idx[b * LL + l0 + t];
    m_r[t]  = mask[b * LL + l0 + t];
  }

  float4 acc = {0.f, 0.f, 0.f, 0.f};
  float ys = 0.f;
  #pragma unroll
  for (int g = 0; g < FTOK_WAVE; g += FPF) {
    float4 v[FPF];
    #pragma unroll
    for (int t = 0; t < FPF; ++t)
      v[t] = enc4[(size_t)id_r[g + t] * (DD / 4) + lane];
    #pragma unroll
    for (int t = 0; t < FPF; ++t) {
      const float m = m_r[g + t];
      float d = v[t].x * es.x + v[t].y * es.y + v[t].z * es.z + v[t].w * es.w;
      #pragma unroll
      for (int off = 32; off > 0; off >>= 1) d += __shfl_xor(d, off);
      const float score = d * m;
      const float y = expf(score) * m;
      const float ym = y * m;
      acc.x += ym * v[t].x; acc.y += ym * v[t].y;
      acc.z += ym * v[t].z; acc.w += ym * v[t].w;
      ys += y;
    }
  }

  __shared__ float lds[4][DD];
  __shared__ float ylds[4];
  lds[wave][lane * 4 + 0] = acc.x;
  lds[wave][lane * 4 + 1] = acc.y;
  lds[wave][lane * 4 + 2] = acc.z;
  lds[wave][lane * 4 + 3] = acc.w;
  if (lane == 0) ylds[wave] = ys;
  __syncthreads();

  const float s = lds[0][tid] + lds[1][tid] + lds[2][tid] + lds[3][tid];
  pout[(chunk * BB + b) * DD + tid] = s;
  if (tid == 0) pys[chunk * BB + b] = ylds[0] + ylds[1] + ylds[2] + ylds[3];
}

__global__ __launch_bounds__(TPB) void kR2head(
    const float* __restrict__ pout, const float* __restrict__ pys,
    const float* __restrict__ emb_sum, const float* __restrict__ lens,
    const float* __restrict__ dec_w, float* __restrict__ out) {
  const int b = blockIdx.x;
  const int tid = threadIdx.x;
  const int wave = tid >> 6;
  const int lane = tid & 63;

  float os = 0.f;
  #pragma unroll
  for (int c = 0; c < FSPLIT; ++c) os += pout[(c * BB + b) * DD + tid];

  __shared__ float ysum_s;
  __shared__ __align__(16) float vec[DD];
  if (tid < 64) {
    float v = (tid < FSPLIT) ? pys[tid * BB + b] : 0.f;
    #pragma unroll
    for (int off = 16; off > 0; off >>= 1) v += __shfl_xor(v, off);
    if (tid == 0) ysum_s = v;
  }
  __syncthreads();

  vec[tid] = os / ysum_s + emb_sum[b * DD + tid] / lens[b];
  __syncthreads();

  const float4 vv = *reinterpret_cast<const float4*>(&vec[lane * 4]);
  #pragma unroll
  for (int cc = 0; cc < 4; ++cc) {
    const int c = wave * 4 + cc;
    const float4 dw = reinterpret_cast<const float4*>(dec_w)[c * (DD / 4) + lane];
    float d = vv.x * dw.x + vv.y * dw.y + vv.z * dw.z + vv.w * dw.w;
    #pragma unroll
    for (int off = 32; off > 0; off >>= 1) d += __shfl_xor(d, off);
    if (lane == 0) out[b * NC + c] = d;
  }
}

extern "C" void kernel_launch(void* const* d_in, const int* in_sizes, int n_in,
                              void* d_out, int out_size, void* d_ws, size_t ws_size,
                              hipStream_t stream) {
  const int*    idx   = (const int*)d_in[0];
  const float*  mask  = (const float*)d_in[1];
  const float4* enc4  = (const float4*)d_in[2];
  const float*  dec_w = (const float*)d_in[3];
  float* out = (float*)d_out;

  float* ws = (float*)d_ws;
  float* pes     = ws;                        // 32*BB*DD
  float* plen    = pes + 32 * BB * DD;        // 32*BB
  float* pout    = plen + 32 * BB;            // 32*BB*DD
  float* pys     = pout + 32 * BB * DD;       // 32*BB
  float* emb_sum = pys + 32 * BB;             // BB*DD (fallback)
  float* lens    = emb_sum + BB * DD;         // BB   (fallback)

  void* args[] = { (void*)&idx, (void*)&mask, (void*)&enc4, (void*)&dec_w,
                   (void*)&pes, (void*)&plen, (void*)&pout, (void*)&pys,
                   (void*)&out };
  hipError_t err = hipLaunchCooperativeKernel((const void*)kFused,
                                              dim3(CNBLK), dim3(TPB),
                                              args, (uint32_t)SM_BYTES, stream);
  if (err != hipSuccess) {
    (void)hipGetLastError();   // clear error state, take the proven path
    const dim3 block(TPB);
    const dim3 gridP(BB * FSPLIT);
    hipLaunchKernelGGL(kA_partial, gridP, block, 0, stream,
                       idx, mask, enc4, pes, plen);
    hipLaunchKernelGGL(kR1, dim3(BB), block, 0, stream, pes, plen, emb_sum, lens);
    hipLaunchKernelGGL(kB_partial, gridP, block, 0, stream,
                       idx, mask, enc4, emb_sum, pout, pys);
    hipLaunchKernelGGL(kR2head, dim3(BB), block, 0, stream,
                       pout, pys, emb_sum, lens, dec_w, out);
  }
}

// Round 9
// 52.030 us; speedup vs baseline: 2.8055x; 2.8055x over previous
//
#include <hip/hip_runtime.h>
#include <math.h>

#define BB 32
#define LL 2048
#define DD 256
#define NC 16
#define TPB 256   // 4 waves

#define SPLIT 64                        // chunks per batch row
#define NBLK  (BB * SPLIT)              // 2048 blocks = 8 blocks/CU
#define TOK_CHUNK (LL / SPLIT)          // 32 tokens per block
#define TOK_WAVE  (TOK_CHUNK / 4)       // 8 tokens per wave, all in flight

// ws layout (floats):
//  pes  [SPLIT][BB][DD] | plen [SPLIT][BB] | pout [SPLIT][BB][DD] | pys [SPLIT][BB]
//  emb_sum [BB][DD] | lens [BB]

__global__ __launch_bounds__(TPB) void kA_partial(
    const int* __restrict__ idx, const float* __restrict__ mask,
    const float4* __restrict__ enc4,
    float* __restrict__ pes, float* __restrict__ plen) {
  const int b     = blockIdx.x / SPLIT;
  const int chunk = blockIdx.x % SPLIT;
  const int wave  = threadIdx.x >> 6;
  const int lane  = threadIdx.x & 63;
  const int tid   = threadIdx.x;
  const int l0 = chunk * TOK_CHUNK + wave * TOK_WAVE;

  int   id_r[TOK_WAVE];
  float m_r[TOK_WAVE];
  #pragma unroll
  for (int t = 0; t < TOK_WAVE; ++t) {
    id_r[t] = idx[b * LL + l0 + t];
    m_r[t]  = mask[b * LL + l0 + t];
  }
  float4 v_r[TOK_WAVE];                 // all 8 gathers in flight
  #pragma unroll
  for (int t = 0; t < TOK_WAVE; ++t)
    v_r[t] = enc4[(size_t)id_r[t] * (DD / 4) + lane];

  float4 acc = {0.f, 0.f, 0.f, 0.f};
  float lenacc = 0.f;
  #pragma unroll
  for (int t = 0; t < TOK_WAVE; ++t) {
    const float m = m_r[t];
    acc.x += v_r[t].x * m; acc.y += v_r[t].y * m;
    acc.z += v_r[t].z * m; acc.w += v_r[t].w * m;
    lenacc += m;
  }

  __shared__ float lds[4][DD];
  __shared__ float llds[4];
  lds[wave][lane * 4 + 0] = acc.x;
  lds[wave][lane * 4 + 1] = acc.y;
  lds[wave][lane * 4 + 2] = acc.z;
  lds[wave][lane * 4 + 3] = acc.w;
  if (lane == 0) llds[wave] = lenacc;   // identical across lanes of a wave
  __syncthreads();

  const float s = lds[0][tid] + lds[1][tid] + lds[2][tid] + lds[3][tid];
  pes[(chunk * BB + b) * DD + tid] = s;
  if (tid == 0) plen[chunk * BB + b] = llds[0] + llds[1] + llds[2] + llds[3];
}

__global__ __launch_bounds__(TPB) void kR1(
    const float* __restrict__ pes, const float* __restrict__ plen,
    float* __restrict__ emb_sum, float* __restrict__ lens) {
  const int b = blockIdx.x;
  const int tid = threadIdx.x;
  float s = 0.f;
  #pragma unroll
  for (int c = 0; c < SPLIT; ++c) s += pes[(c * BB + b) * DD + tid];
  emb_sum[b * DD + tid] = s;
  if (tid < 64) {
    float v = plen[tid * BB + b];       // SPLIT == 64: all lanes valid
    #pragma unroll
    for (int off = 32; off > 0; off >>= 1) v += __shfl_xor(v, off);
    if (tid == 0) lens[b] = v;
  }
}

__global__ __launch_bounds__(TPB) void kB_partial(
    const int* __restrict__ idx, const float* __restrict__ mask,
    const float4* __restrict__ enc4, const float* __restrict__ emb_sum,
    float* __restrict__ pout, float* __restrict__ pys) {
  const int b     = blockIdx.x / SPLIT;
  const int chunk = blockIdx.x % SPLIT;
  const int wave  = threadIdx.x >> 6;
  const int lane  = threadIdx.x & 63;
  const int tid   = threadIdx.x;
  const int l0 = chunk * TOK_CHUNK + wave * TOK_WAVE;

  const float4 es = reinterpret_cast<const float4*>(emb_sum)[b * (DD / 4) + lane];

  int   id_r[TOK_WAVE];
  float m_r[TOK_WAVE];
  #pragma unroll
  for (int t = 0; t < TOK_WAVE; ++t) {
    id_r[t] = idx[b * LL + l0 + t];
    m_r[t]  = mask[b * LL + l0 + t];
  }
  float4 v_r[TOK_WAVE];                 // all 8 gathers in flight
  #pragma unroll
  for (int t = 0; t < TOK_WAVE; ++t)
    v_r[t] = enc4[(size_t)id_r[t] * (DD / 4) + lane];

  float4 acc = {0.f, 0.f, 0.f, 0.f};
  float ys = 0.f;
  #pragma unroll
  for (int t = 0; t < TOK_WAVE; ++t) {
    const float m = m_r[t];
    const float4 v = v_r[t];
    float d = v.x * es.x + v.y * es.y + v.z * es.z + v.w * es.w;
    #pragma unroll
    for (int off = 32; off > 0; off >>= 1) d += __shfl_xor(d, off);
    const float score = d * m;          // emb_l . emb_sum  (emb_l = m*row)
    const float y = expf(score) * m;    // y = exp(scores) * mask
    const float ym = y * m;             // weight on raw row
    acc.x += ym * v.x; acc.y += ym * v.y;
    acc.z += ym * v.z; acc.w += ym * v.w;
    ys += y;                            // identical across lanes
  }

  __shared__ float lds[4][DD];
  __shared__ float ylds[4];
  lds[wave][lane * 4 + 0] = acc.x;
  lds[wave][lane * 4 + 1] = acc.y;
  lds[wave][lane * 4 + 2] = acc.z;
  lds[wave][lane * 4 + 3] = acc.w;
  if (lane == 0) ylds[wave] = ys;
  __syncthreads();

  const float s = lds[0][tid] + lds[1][tid] + lds[2][tid] + lds[3][tid];
  pout[(chunk * BB + b) * DD + tid] = s;
  if (tid == 0) pys[chunk * BB + b] = ylds[0] + ylds[1] + ylds[2] + ylds[3];
}

__global__ __launch_bounds__(TPB) void kR2head(
    const float* __restrict__ pout, const float* __restrict__ pys,
    const float* __restrict__ emb_sum, const float* __restrict__ lens,
    const float* __restrict__ dec_w, float* __restrict__ out) {
  const int b = blockIdx.x;
  const int tid = threadIdx.x;
  const int wave = tid >> 6;
  const int lane = tid & 63;

  float os = 0.f;
  #pragma unroll
  for (int c = 0; c < SPLIT; ++c) os += pout[(c * BB + b) * DD + tid];

  __shared__ float ysum_s;
  __shared__ __align__(16) float vec[DD];
  if (tid < 64) {
    float v = pys[tid * BB + b];        // SPLIT == 64: all lanes valid
    #pragma unroll
    for (int off = 32; off > 0; off >>= 1) v += __shfl_xor(v, off);
    if (tid == 0) ysum_s = v;
  }
  __syncthreads();

  vec[tid] = os / ysum_s + emb_sum[b * DD + tid] / lens[b];
  __syncthreads();

  // head: wave w computes classes 4w .. 4w+3
  const float4 vv = *reinterpret_cast<const float4*>(&vec[lane * 4]);
  #pragma unroll
  for (int cc = 0; cc < 4; ++cc) {
    const int c = wave * 4 + cc;
    const float4 dw = reinterpret_cast<const float4*>(dec_w)[c * (DD / 4) + lane];
    float d = vv.x * dw.x + vv.y * dw.y + vv.z * dw.z + vv.w * dw.w;
    #pragma unroll
    for (int off = 32; off > 0; off >>= 1) d += __shfl_xor(d, off);
    if (lane == 0) out[b * NC + c] = d;
  }
}

extern "C" void kernel_launch(void* const* d_in, const int* in_sizes, int n_in,
                              void* d_out, int out_size, void* d_ws, size_t ws_size,
                              hipStream_t stream) {
  const int*    idx   = (const int*)d_in[0];
  const float*  mask  = (const float*)d_in[1];
  const float4* enc4  = (const float4*)d_in[2];
  const float*  dec_w = (const float*)d_in[3];
  float* out = (float*)d_out;

  float* ws = (float*)d_ws;
  float* pes     = ws;                        // SPLIT*BB*DD
  float* plen    = pes + SPLIT * BB * DD;     // SPLIT*BB
  float* pout    = plen + SPLIT * BB;         // SPLIT*BB*DD
  float* pys     = pout + SPLIT * BB * DD;    // SPLIT*BB
  float* emb_sum = pys + SPLIT * BB;          // BB*DD
  float* lens    = emb_sum + BB * DD;         // BB

  const dim3 block(TPB);
  hipLaunchKernelGGL(kA_partial, dim3(NBLK), block, 0, stream,
                     idx, mask, enc4, pes, plen);
  hipLaunchKernelGGL(kR1, dim3(BB), block, 0, stream, pes, plen, emb_sum, lens);
  hipLaunchKernelGGL(kB_partial, dim3(NBLK), block, 0, stream,
                     idx, mask, enc4, emb_sum, pout, pys);
  hipLaunchKernelGGL(kR2head, dim3(BB), block, 0, stream,
                     pout, pys, emb_sum, lens, dec_w, out);
}

// Round 10
// 34.009 us; speedup vs baseline: 4.2920x; 1.5299x over previous
//
#include <hip/hip_runtime.h>
#include <math.h>

#define BB 32
#define LL 2048
#define DD 256
#define NC 16
#define TPB 256   // 4 waves

#define SPLIT 32                        // proven sweet spot (16->36us, 32->33us, 64->52us)
#define NBLK  (BB * SPLIT)              // 1024 blocks
#define TOK_CHUNK (LL / SPLIT)          // 64 tokens per block
#define TOK_WAVE  (TOK_CHUNK / 4)       // 16 tokens per wave — ALL in flight

// ws layout (floats):
//  pes  [SPLIT][BB][DD] | plen [SPLIT][BB] | pout [SPLIT][BB][DD] | pys [SPLIT][BB]
//  emb_sum [BB][DD] | lens [BB]

__global__ __launch_bounds__(TPB) void kA_partial(
    const int* __restrict__ idx, const float* __restrict__ mask,
    const float4* __restrict__ enc4,
    float* __restrict__ pes, float* __restrict__ plen) {
  const int b     = blockIdx.x / SPLIT;
  const int chunk = blockIdx.x % SPLIT;
  const int wave  = threadIdx.x >> 6;
  const int lane  = threadIdx.x & 63;
  const int tid   = threadIdx.x;
  const int l0 = chunk * TOK_CHUNK + wave * TOK_WAVE;

  int   id_r[TOK_WAVE];
  float m_r[TOK_WAVE];
  #pragma unroll
  for (int t = 0; t < TOK_WAVE; ++t) {
    id_r[t] = idx[b * LL + l0 + t];
    m_r[t]  = mask[b * LL + l0 + t];
  }
  // all 16 gathers issued back-to-back, no accumulate in between
  float4 v_r[TOK_WAVE];
  #pragma unroll
  for (int t = 0; t < TOK_WAVE; ++t)
    v_r[t] = enc4[(size_t)id_r[t] * (DD / 4) + lane];

  float4 acc = {0.f, 0.f, 0.f, 0.f};
  float lenacc = 0.f;
  #pragma unroll
  for (int t = 0; t < TOK_WAVE; ++t) {
    const float m = m_r[t];
    acc.x += v_r[t].x * m; acc.y += v_r[t].y * m;
    acc.z += v_r[t].z * m; acc.w += v_r[t].w * m;
    lenacc += m;
  }

  __shared__ float lds[4][DD];
  __shared__ float llds[4];
  lds[wave][lane * 4 + 0] = acc.x;
  lds[wave][lane * 4 + 1] = acc.y;
  lds[wave][lane * 4 + 2] = acc.z;
  lds[wave][lane * 4 + 3] = acc.w;
  if (lane == 0) llds[wave] = lenacc;
  __syncthreads();

  const float s = lds[0][tid] + lds[1][tid] + lds[2][tid] + lds[3][tid];
  pes[(chunk * BB + b) * DD + tid] = s;
  if (tid == 0) plen[chunk * BB + b] = llds[0] + llds[1] + llds[2] + llds[3];
}

__global__ __launch_bounds__(TPB) void kR1(
    const float* __restrict__ pes, const float* __restrict__ plen,
    float* __restrict__ emb_sum, float* __restrict__ lens) {
  const int b = blockIdx.x;
  const int tid = threadIdx.x;
  float s = 0.f;
  #pragma unroll
  for (int c = 0; c < SPLIT; ++c) s += pes[(c * BB + b) * DD + tid];
  emb_sum[b * DD + tid] = s;
  if (tid < 64) {
    float v = (tid < SPLIT) ? plen[tid * BB + b] : 0.f;
    #pragma unroll
    for (int off = 16; off > 0; off >>= 1) v += __shfl_xor(v, off);
    if (tid == 0) lens[b] = v;
  }
}

__global__ __launch_bounds__(TPB) void kB_partial(
    const int* __restrict__ idx, const float* __restrict__ mask,
    const float4* __restrict__ enc4, const float* __restrict__ emb_sum,
    float* __restrict__ pout, float* __restrict__ pys) {
  const int b     = blockIdx.x / SPLIT;
  const int chunk = blockIdx.x % SPLIT;
  const int wave  = threadIdx.x >> 6;
  const int lane  = threadIdx.x & 63;
  const int tid   = threadIdx.x;
  const int l0 = chunk * TOK_CHUNK + wave * TOK_WAVE;

  // es staged in LDS once per block (one 1KB load instead of 4)
  __shared__ __align__(16) float esb[DD];
  if (tid < DD) {
    // wave 0..3 all participate: 256 threads load 256 floats coalesced
    esb[tid] = emb_sum[b * DD + tid];
  }
  __syncthreads();
  const float4 es = *reinterpret_cast<const float4*>(&esb[lane * 4]);

  int   id_r[TOK_WAVE];
  float m_r[TOK_WAVE];
  #pragma unroll
  for (int t = 0; t < TOK_WAVE; ++t) {
    id_r[t] = idx[b * LL + l0 + t];
    m_r[t]  = mask[b * LL + l0 + t];
  }
  // all 16 gathers in flight
  float4 v_r[TOK_WAVE];
  #pragma unroll
  for (int t = 0; t < TOK_WAVE; ++t)
    v_r[t] = enc4[(size_t)id_r[t] * (DD / 4) + lane];

  float4 acc = {0.f, 0.f, 0.f, 0.f};
  float ys = 0.f;
  #pragma unroll
  for (int t = 0; t < TOK_WAVE; ++t) {
    const float m = m_r[t];
    const float4 v = v_r[t];
    float d = v.x * es.x + v.y * es.y + v.z * es.z + v.w * es.w;
    #pragma unroll
    for (int off = 32; off > 0; off >>= 1) d += __shfl_xor(d, off);
    const float score = d * m;          // emb_l . emb_sum  (emb_l = m*row)
    const float y = expf(score) * m;    // y = exp(scores) * mask
    const float ym = y * m;             // weight on raw row
    acc.x += ym * v.x; acc.y += ym * v.y;
    acc.z += ym * v.z; acc.w += ym * v.w;
    ys += y;                            // identical across lanes
  }

  __shared__ float lds[4][DD];
  __shared__ float ylds[4];
  lds[wave][lane * 4 + 0] = acc.x;
  lds[wave][lane * 4 + 1] = acc.y;
  lds[wave][lane * 4 + 2] = acc.z;
  lds[wave][lane * 4 + 3] = acc.w;
  if (lane == 0) ylds[wave] = ys;
  __syncthreads();

  const float s = lds[0][tid] + lds[1][tid] + lds[2][tid] + lds[3][tid];
  pout[(chunk * BB + b) * DD + tid] = s;
  if (tid == 0) pys[chunk * BB + b] = ylds[0] + ylds[1] + ylds[2] + ylds[3];
}

__global__ __launch_bounds__(TPB) void kR2head(
    const float* __restrict__ pout, const float* __restrict__ pys,
    const float* __restrict__ emb_sum, const float* __restrict__ lens,
    const float* __restrict__ dec_w, float* __restrict__ out) {
  const int b = blockIdx.x;
  const int tid = threadIdx.x;
  const int wave = tid >> 6;
  const int lane = tid & 63;

  float os = 0.f;
  #pragma unroll
  for (int c = 0; c < SPLIT; ++c) os += pout[(c * BB + b) * DD + tid];

  __shared__ float ysum_s;
  __shared__ __align__(16) float vec[DD];
  if (tid < 64) {
    float v = (tid < SPLIT) ? pys[tid * BB + b] : 0.f;
    #pragma unroll
    for (int off = 16; off > 0; off >>= 1) v += __shfl_xor(v, off);
    if (tid == 0) ysum_s = v;
  }
  __syncthreads();

  vec[tid] = os / ysum_s + emb_sum[b * DD + tid] / lens[b];
  __syncthreads();

  const float4 vv = *reinterpret_cast<const float4*>(&vec[lane * 4]);
  #pragma unroll
  for (int cc = 0; cc < 4; ++cc) {
    const int c = wave * 4 + cc;
    const float4 dw = reinterpret_cast<const float4*>(dec_w)[c * (DD / 4) + lane];
    float d = vv.x * dw.x + vv.y * dw.y + vv.z * dw.z + vv.w * dw.w;
    #pragma unroll
    for (int off = 32; off > 0; off >>= 1) d += __shfl_xor(d, off);
    if (lane == 0) out[b * NC + c] = d;
  }
}

extern "C" void kernel_launch(void* const* d_in, const int* in_sizes, int n_in,
                              void* d_out, int out_size, void* d_ws, size_t ws_size,
                              hipStream_t stream) {
  const int*    idx   = (const int*)d_in[0];
  const float*  mask  = (const float*)d_in[1];
  const float4* enc4  = (const float4*)d_in[2];
  const float*  dec_w = (const float*)d_in[3];
  float* out = (float*)d_out;

  float* ws = (float*)d_ws;
  float* pes     = ws;                        // SPLIT*BB*DD
  float* plen    = pes + SPLIT * BB * DD;     // SPLIT*BB
  float* pout    = plen + SPLIT * BB;         // SPLIT*BB*DD
  float* pys     = pout + SPLIT * BB * DD;    // SPLIT*BB
  float* emb_sum = pys + SPLIT * BB;          // BB*DD
  float* lens    = emb_sum + BB * DD;         // BB

  const dim3 block(TPB);
  hipLaunchKernelGGL(kA_partial, dim3(NBLK), block, 0, stream,
                     idx, mask, enc4, pes, plen);
  hipLaunchKernelGGL(kR1, dim3(BB), block, 0, stream, pes, plen, emb_sum, lens);
  hipLaunchKernelGGL(kB_partial, dim3(NBLK), block, 0, stream,
                     idx, mask, enc4, emb_sum, pout, pys);
  hipLaunchKernelGGL(kR2head, dim3(BB), block, 0, stream,
                     pout, pys, emb_sum, lens, dec_w, out);
}

// Round 11
// 31.677 us; speedup vs baseline: 4.6080x; 1.0736x over previous
//
#include <hip/hip_runtime.h>
#include <math.h>

#define BB 32
#define LL 2048
#define DD 256
#define NC 16
#define TPB 256    // gather kernels: 4 waves
#define TPR 1024   // reduce kernels: 16 waves

#define SPLIT 32                        // proven sweet spot
#define NBLK  (BB * SPLIT)              // 1024 blocks
#define TOK_CHUNK (LL / SPLIT)          // 64 tokens per block
#define TOK_WAVE  (TOK_CHUNK / 4)       // 16 tokens per wave — all in flight

// ws layout (floats), partials TRANSPOSED to [b][chunk][d] for contiguous reduce reads:
//  pes  [BB][SPLIT][DD] | plen [BB][SPLIT] | pout [BB][SPLIT][DD] | pys [BB][SPLIT]
//  emb_sum [BB][DD] | lens [BB]

__global__ __launch_bounds__(TPB) void kA_partial(
    const int* __restrict__ idx, const float* __restrict__ mask,
    const float4* __restrict__ enc4,
    float* __restrict__ pes, float* __restrict__ plen) {
  const int b     = blockIdx.x / SPLIT;
  const int chunk = blockIdx.x % SPLIT;
  const int wave  = threadIdx.x >> 6;
  const int lane  = threadIdx.x & 63;
  const int tid   = threadIdx.x;
  const int l0 = chunk * TOK_CHUNK + wave * TOK_WAVE;

  int   id_r[TOK_WAVE];
  float m_r[TOK_WAVE];
  #pragma unroll
  for (int t = 0; t < TOK_WAVE; ++t) {
    id_r[t] = idx[b * LL + l0 + t];
    m_r[t]  = mask[b * LL + l0 + t];
  }
  float4 v_r[TOK_WAVE];                 // all 16 gathers in flight
  #pragma unroll
  for (int t = 0; t < TOK_WAVE; ++t)
    v_r[t] = enc4[(size_t)id_r[t] * (DD / 4) + lane];

  float4 acc = {0.f, 0.f, 0.f, 0.f};
  float lenacc = 0.f;
  #pragma unroll
  for (int t = 0; t < TOK_WAVE; ++t) {
    const float m = m_r[t];
    acc.x += v_r[t].x * m; acc.y += v_r[t].y * m;
    acc.z += v_r[t].z * m; acc.w += v_r[t].w * m;
    lenacc += m;
  }

  __shared__ float lds[4][DD];
  __shared__ float llds[4];
  lds[wave][lane * 4 + 0] = acc.x;
  lds[wave][lane * 4 + 1] = acc.y;
  lds[wave][lane * 4 + 2] = acc.z;
  lds[wave][lane * 4 + 3] = acc.w;
  if (lane == 0) llds[wave] = lenacc;
  __syncthreads();

  const float s = lds[0][tid] + lds[1][tid] + lds[2][tid] + lds[3][tid];
  pes[(b * SPLIT + chunk) * DD + tid] = s;                 // transposed layout
  if (tid == 0) plen[b * SPLIT + chunk] = llds[0] + llds[1] + llds[2] + llds[3];
}

__global__ __launch_bounds__(TPR) void kR1(
    const float* __restrict__ pes, const float* __restrict__ plen,
    float* __restrict__ emb_sum, float* __restrict__ lens) {
  const int b   = blockIdx.x;
  const int tid = threadIdx.x;
  const int q   = tid >> 8;       // 0..3
  const int d   = tid & 255;

  float s = 0.f;
  #pragma unroll
  for (int c = q * 8; c < q * 8 + 8; ++c)
    s += pes[(b * SPLIT + c) * DD + d];   // contiguous 32KB span per block

  __shared__ float red[4][DD];
  red[q][d] = s;

  float lv = 0.f;
  if (tid < 64) {
    lv = (tid < SPLIT) ? plen[b * SPLIT + tid] : 0.f;
    #pragma unroll
    for (int off = 32; off > 0; off >>= 1) lv += __shfl_xor(lv, off);
    if (tid == 0) lens[b] = lv;
  }
  __syncthreads();
  if (q == 0) emb_sum[b * DD + d] = red[0][d] + red[1][d] + red[2][d] + red[3][d];
}

__global__ __launch_bounds__(TPB) void kB_partial(
    const int* __restrict__ idx, const float* __restrict__ mask,
    const float4* __restrict__ enc4, const float* __restrict__ emb_sum,
    float* __restrict__ pout, float* __restrict__ pys) {
  const int b     = blockIdx.x / SPLIT;
  const int chunk = blockIdx.x % SPLIT;
  const int wave  = threadIdx.x >> 6;
  const int lane  = threadIdx.x & 63;
  const int tid   = threadIdx.x;
  const int l0 = chunk * TOK_CHUNK + wave * TOK_WAVE;

  __shared__ __align__(16) float esb[DD];
  esb[tid] = emb_sum[b * DD + tid];
  __syncthreads();
  const float4 es = *reinterpret_cast<const float4*>(&esb[lane * 4]);

  int   id_r[TOK_WAVE];
  float m_r[TOK_WAVE];
  #pragma unroll
  for (int t = 0; t < TOK_WAVE; ++t) {
    id_r[t] = idx[b * LL + l0 + t];
    m_r[t]  = mask[b * LL + l0 + t];
  }
  float4 v_r[TOK_WAVE];                 // all 16 gathers in flight
  #pragma unroll
  for (int t = 0; t < TOK_WAVE; ++t)
    v_r[t] = enc4[(size_t)id_r[t] * (DD / 4) + lane];

  float4 acc = {0.f, 0.f, 0.f, 0.f};
  float ys = 0.f;
  #pragma unroll
  for (int t = 0; t < TOK_WAVE; ++t) {
    const float m = m_r[t];
    const float4 v = v_r[t];
    float d = v.x * es.x + v.y * es.y + v.z * es.z + v.w * es.w;
    #pragma unroll
    for (int off = 32; off > 0; off >>= 1) d += __shfl_xor(d, off);
    const float score = d * m;          // emb_l . emb_sum  (emb_l = m*row)
    const float y = expf(score) * m;    // y = exp(scores) * mask
    const float ym = y * m;             // weight on raw row
    acc.x += ym * v.x; acc.y += ym * v.y;
    acc.z += ym * v.z; acc.w += ym * v.w;
    ys += y;                            // identical across lanes
  }

  __shared__ float lds[4][DD];
  __shared__ float ylds[4];
  lds[wave][lane * 4 + 0] = acc.x;
  lds[wave][lane * 4 + 1] = acc.y;
  lds[wave][lane * 4 + 2] = acc.z;
  lds[wave][lane * 4 + 3] = acc.w;
  if (lane == 0) ylds[wave] = ys;
  __syncthreads();

  const float s = lds[0][tid] + lds[1][tid] + lds[2][tid] + lds[3][tid];
  pout[(b * SPLIT + chunk) * DD + tid] = s;                // transposed layout
  if (tid == 0) pys[b * SPLIT + chunk] = ylds[0] + ylds[1] + ylds[2] + ylds[3];
}

__global__ __launch_bounds__(TPR) void kR2head(
    const float* __restrict__ pout, const float* __restrict__ pys,
    const float* __restrict__ emb_sum, const float* __restrict__ lens,
    const float* __restrict__ dec_w, float* __restrict__ out) {
  const int b   = blockIdx.x;
  const int tid = threadIdx.x;
  const int q   = tid >> 8;       // 0..3
  const int d   = tid & 255;

  float s = 0.f;
  #pragma unroll
  for (int c = q * 8; c < q * 8 + 8; ++c)
    s += pout[(b * SPLIT + c) * DD + d];  // contiguous 32KB span

  __shared__ float red[4][DD];
  __shared__ __align__(16) float vec[DD];
  __shared__ float ysum_s;
  red[q][d] = s;

  if (tid < 64) {
    float v = (tid < SPLIT) ? pys[b * SPLIT + tid] : 0.f;
    #pragma unroll
    for (int off = 32; off > 0; off >>= 1) v += __shfl_xor(v, off);
    if (tid == 0) ysum_s = v;
  }
  __syncthreads();

  if (q == 0) {
    const float os = red[0][d] + red[1][d] + red[2][d] + red[3][d];
    vec[d] = os / ysum_s + emb_sum[b * DD + d] / lens[b];
  }
  __syncthreads();

  // head: 16 waves, one class per wave
  const int wave = tid >> 6;      // 0..15 == class
  const int lane = tid & 63;
  const float4 vv = *reinterpret_cast<const float4*>(&vec[lane * 4]);
  const float4 dw = reinterpret_cast<const float4*>(dec_w)[wave * (DD / 4) + lane];
  float dsum = vv.x * dw.x + vv.y * dw.y + vv.z * dw.z + vv.w * dw.w;
  #pragma unroll
  for (int off = 32; off > 0; off >>= 1) dsum += __shfl_xor(dsum, off);
  if (lane == 0) out[b * NC + wave] = dsum;
}

extern "C" void kernel_launch(void* const* d_in, const int* in_sizes, int n_in,
                              void* d_out, int out_size, void* d_ws, size_t ws_size,
                              hipStream_t stream) {
  const int*    idx   = (const int*)d_in[0];
  const float*  mask  = (const float*)d_in[1];
  const float4* enc4  = (const float4*)d_in[2];
  const float*  dec_w = (const float*)d_in[3];
  float* out = (float*)d_out;

  float* ws = (float*)d_ws;
  float* pes     = ws;                        // BB*SPLIT*DD
  float* plen    = pes + BB * SPLIT * DD;     // BB*SPLIT
  float* pout    = plen + BB * SPLIT;         // BB*SPLIT*DD
  float* pys     = pout + BB * SPLIT * DD;    // BB*SPLIT
  float* emb_sum = pys + BB * SPLIT;          // BB*DD
  float* lens    = emb_sum + BB * DD;         // BB

  hipLaunchKernelGGL(kA_partial, dim3(NBLK), dim3(TPB), 0, stream,
                     idx, mask, enc4, pes, plen);
  hipLaunchKernelGGL(kR1, dim3(BB), dim3(TPR), 0, stream, pes, plen, emb_sum, lens);
  hipLaunchKernelGGL(kB_partial, dim3(NBLK), dim3(TPB), 0, stream,
                     idx, mask, enc4, emb_sum, pout, pys);
  hipLaunchKernelGGL(kR2head, dim3(BB), dim3(TPR), 0, stream,
                     pout, pys, emb_sum, lens, dec_w, out);
}